// Round 16
// baseline (241.892 us; speedup 1.0000x reference)
//
#include <hip/hip_runtime.h>
#include <stdint.h>

#define DIMN 1024
#define HDN 64
#define SLEN 2048
#define NKT (SLEN / 64)

typedef _Float16 f16;
typedef __attribute__((ext_vector_type(8))) _Float16 f16x8;
typedef __attribute__((ext_vector_type(4))) _Float16 f16x4;
typedef __attribute__((ext_vector_type(2))) _Float16 f16x2;
typedef __attribute__((ext_vector_type(2))) __fp16 h16x2;   // cvt_pkrtz's native type
typedef __attribute__((ext_vector_type(4))) float f32x4;
typedef __attribute__((ext_vector_type(16))) float f32x16;
typedef __attribute__((ext_vector_type(4))) float f4;
typedef __attribute__((ext_vector_type(4))) unsigned int u32x4;

#define PA 48   // GEMM A LDS row stride (elems), 96B

__device__ __forceinline__ f16x2 pk2(float a, float b) {
  h16x2 t = __builtin_amdgcn_cvt_pkrtz(a, b);
  return __builtin_bit_cast(f16x2, t);
}
__device__ __forceinline__ unsigned int pk2u(float a, float b) {
  h16x2 t = __builtin_amdgcn_cvt_pkrtz(a, b);
  return __builtin_bit_cast(unsigned int, t);
}
__device__ __forceinline__ f16x4 pk4(float a, float b, float c, float d) {
  f16x2 x = pk2(a, b), y = pk2(c, d);
  f16x4 r; r[0] = x[0]; r[1] = x[1]; r[2] = y[0]; r[3] = y[1]; return r;
}
__device__ __forceinline__ f16x8 pk8(f4 x, f4 y) {
  f16x2 a = pk2(x[0], x[1]), b = pk2(x[2], x[3]);
  f16x2 c = pk2(y[0], y[1]), d = pk2(y[2], y[3]);
  f16x8 r; r[0] = a[0]; r[1] = a[1]; r[2] = b[0]; r[3] = b[1];
  r[4] = c[0]; r[5] = c[1]; r[6] = d[0]; r[7] = d[1]; return r;
}

// ---------- transpose + convert weights: WT[n][k] = (f16)W[k][n] ----------
__global__ __launch_bounds__(256) void k_wt(const float* __restrict__ W0, const float* __restrict__ W1,
                                            const float* __restrict__ W2, const float* __restrict__ W3,
                                            f16* __restrict__ WT) {
  __shared__ f16 tile[64][65];
  const float* W = (blockIdx.z == 0) ? W0 : (blockIdx.z == 1) ? W1 : (blockIdx.z == 2) ? W2 : W3;
  f16* T = WT + (size_t)blockIdx.z * DIMN * DIMN;
  int n0 = blockIdx.x * 64, k0 = blockIdx.y * 64;
  int tx = threadIdx.x & 63, ty = threadIdx.x >> 6;
  for (int i = ty; i < 64; i += 4)
    tile[i][tx] = (f16)(W[(size_t)(k0 + i) * DIMN + n0 + tx]);
  __syncthreads();
  for (int i = ty; i < 64; i += 4)
    T[(size_t)(n0 + i) * DIMN + k0 + tx] = tile[tx][i];
}

// ---------- fused QKV projection: one dispatch, 3 GEMMs (R12-exact, best wall) ----------
// Natural dispatch order (no swizzle: R14's swizzle exploded FETCH 4x; R15's T14
// pipeline regressed wall). widx = by>>3 selects {q,k,v}.
__global__ __launch_bounds__(256) void k_qkv(const float* __restrict__ qin, const float* __restrict__ kin,
                                             const float* __restrict__ vin, const f16* __restrict__ WT,
                                             f16* __restrict__ Qh, f16* __restrict__ Kh,
                                             f16* __restrict__ VhT) {
  __shared__ alignas(16) f16 As[128 * PA];
  __shared__ alignas(16) f16 Bs[128 * 32];
  const int tid = threadIdx.x;
  const int lane = tid & 63, wid = tid >> 6;
  const int wr = wid >> 1, wc = wid & 1;
  const int l15 = lane & 15, lhi = lane >> 4;
  const int widx = blockIdx.y >> 3;
  const float* A = (widx == 0) ? qin : (widx == 1) ? kin : vin;
  const f16* BT = WT + (size_t)widx * DIMN * DIMN;
  const int m0 = blockIdx.x * 128, n0 = (blockIdx.y & 7) * 128;
  const int r0 = tid >> 2, c0 = tid & 3;

  f32x4 acc[4][4];
#pragma unroll
  for (int i = 0; i < 4; ++i)
#pragma unroll
    for (int j = 0; j < 4; ++j) { f32x4 z = {0.f, 0.f, 0.f, 0.f}; acc[i][j] = z; }

  for (int kt = 0; kt < DIMN; kt += 32) {
    __syncthreads();
#pragma unroll
    for (int hh = 0; hh < 2; ++hh) {
      int row = hh * 64 + r0;
      __builtin_amdgcn_global_load_lds(
          (const __attribute__((address_space(1))) void*)(BT + (size_t)(n0 + row) * DIMN + kt + c0 * 8),
          (__attribute__((address_space(3))) void*)&Bs[hh * 2048 + tid * 8], 16, 0, 0);
    }
#pragma unroll
    for (int hh = 0; hh < 2; ++hh) {
      int row = r0 + hh * 64;
      const f4* src = (const f4*)(A + (size_t)(m0 + row) * DIMN + kt + c0 * 8);
      f4 a0 = src[0], a1 = src[1];
      *(f16x8*)&As[row * PA + c0 * 8] = pk8(a0, a1);
    }
    __syncthreads();
    f16x8 af[4], bb[4];
#pragma unroll
    for (int mf = 0; mf < 4; ++mf) {
      int row = wr * 64 + mf * 16 + l15;
      af[mf] = *(const f16x8*)&As[row * PA + lhi * 8];
    }
#pragma unroll
    for (int nf = 0; nf < 4; ++nf) {
      int row = wc * 64 + nf * 16 + l15;
      bb[nf] = *(const f16x8*)&Bs[row * 32 + lhi * 8];
    }
#pragma unroll
    for (int mf = 0; mf < 4; ++mf)
#pragma unroll
      for (int nf = 0; nf < 4; ++nf)
        acc[mf][nf] = __builtin_amdgcn_mfma_f32_16x16x32_f16(af[mf], bb[nf], acc[mf][nf], 0, 0, 0);
  }

  if (widx == 2) {
    // V: store C^T per head -> VhT[bh][d][s], s-packed f16x4
#pragma unroll
    for (int mf = 0; mf < 4; ++mf) {
      int rowbase = m0 + wr * 64 + mf * 16 + lhi * 4;
      int bq = rowbase >> 11, sl = rowbase & 2047;
#pragma unroll
      for (int nf = 0; nf < 4; ++nf) {
        int col = n0 + wc * 64 + nf * 16 + l15;
        int bh = bq * 16 + (col >> 6), d = col & 63;
        *(f16x4*)&VhT[((size_t)bh * 64 + d) * SLEN + sl] =
            pk4(acc[mf][nf][0], acc[mf][nf][1], acc[mf][nf][2], acc[mf][nf][3]);
      }
    }
  } else {
    f16* Cp = widx ? Kh : Qh;
#pragma unroll
    for (int mf = 0; mf < 4; ++mf)
#pragma unroll
      for (int r = 0; r < 4; ++r) {
        int row = m0 + wr * 64 + mf * 16 + lhi * 4 + r;
#pragma unroll
        for (int nf = 0; nf < 4; ++nf) {
          int col = n0 + wc * 64 + nf * 16 + l15;
          Cp[(size_t)row * DIMN + col] = (f16)acc[mf][nf][r];
        }
      }
  }
}

// ---------- out-projection GEMM: out[M,1024] f32 = att @ WoT ----------
__global__ __launch_bounds__(256) void k_gemm_out(const f16* __restrict__ A,
                                                  const f16* __restrict__ BT,
                                                  float* __restrict__ Cp) {
  __shared__ alignas(16) f16 As[128 * PA];
  __shared__ alignas(16) f16 Bs[128 * 32];
  const int tid = threadIdx.x;
  const int lane = tid & 63, wid = tid >> 6;
  const int wr = wid >> 1, wc = wid & 1;
  const int l15 = lane & 15, lhi = lane >> 4;
  const int m0 = blockIdx.x * 128, n0 = blockIdx.y * 128;
  const int r0 = tid >> 2, c0 = tid & 3;

  f32x4 acc[4][4];
#pragma unroll
  for (int i = 0; i < 4; ++i)
#pragma unroll
    for (int j = 0; j < 4; ++j) { f32x4 z = {0.f, 0.f, 0.f, 0.f}; acc[i][j] = z; }

  for (int kt = 0; kt < DIMN; kt += 32) {
    __syncthreads();
#pragma unroll
    for (int hh = 0; hh < 2; ++hh) {
      int row = hh * 64 + r0;
      __builtin_amdgcn_global_load_lds(
          (const __attribute__((address_space(1))) void*)(BT + (size_t)(n0 + row) * DIMN + kt + c0 * 8),
          (__attribute__((address_space(3))) void*)&Bs[hh * 2048 + tid * 8], 16, 0, 0);
    }
#pragma unroll
    for (int hh = 0; hh < 2; ++hh) {
      int row = r0 + hh * 64;
      f16x8 vv = *(const f16x8*)(A + (size_t)(m0 + row) * DIMN + kt + c0 * 8);
      *(f16x8*)&As[row * PA + c0 * 8] = vv;
    }
    __syncthreads();
    f16x8 af[4], bb[4];
#pragma unroll
    for (int mf = 0; mf < 4; ++mf) {
      int row = wr * 64 + mf * 16 + l15;
      af[mf] = *(const f16x8*)&As[row * PA + lhi * 8];
    }
#pragma unroll
    for (int nf = 0; nf < 4; ++nf) {
      int row = wc * 64 + nf * 16 + l15;
      bb[nf] = *(const f16x8*)&Bs[row * 32 + lhi * 8];
    }
#pragma unroll
    for (int mf = 0; mf < 4; ++mf)
#pragma unroll
      for (int nf = 0; nf < 4; ++nf)
        acc[mf][nf] = __builtin_amdgcn_mfma_f32_16x16x32_f16(af[mf], bb[nf], acc[mf][nf], 0, 0, 0);
  }
#pragma unroll
  for (int mf = 0; mf < 4; ++mf)
#pragma unroll
    for (int r = 0; r < 4; ++r) {
      int row = m0 + wr * 64 + mf * 16 + lhi * 4 + r;
#pragma unroll
      for (int nf = 0; nf < 4; ++nf) {
        int col = n0 + wc * 64 + nf * 16 + l15;
        Cp[(size_t)row * DIMN + col] = acc[mf][nf][r];
      }
    }
}

// ---------- flash attention: R12 structure + f32 bias (no cvt) + max3 reduction ----------
__global__ __launch_bounds__(256, 4) void k_attn(const f16* __restrict__ Qh, const f16* __restrict__ Kh,
                                                 const f16* __restrict__ VhT, const float* __restrict__ mask,
                                                 f16* __restrict__ att) {
  __shared__ alignas(16) f16 KVs[2][2][64 * 64];  // [buf][K=0/V=1][row][64]
  __shared__ alignas(16) float BiasF[SLEN];       // mask * 1e9*log2e, f32

  const int tid = threadIdx.x;
  const int lane = tid & 63, w = tid >> 6;
  const int l31 = lane & 31, h = lane >> 5;

  const float K2 = 0.18033688f;          // 0.125 * log2(e)
  const float MB = 1.4426950e9f;         // 1e9 * log2(e)
  const float THR = 11.541560f;          // 8 * log2(e)

  const int id = blockIdx.x;
  const int xcd = id & 7, slot = id >> 3;
  const int qt = slot & 15;
  const int bh = xcd * 8 + (slot >> 4);
  const int b = bh >> 4, hh = bh & 15;
  const int q0 = qt * 128;
  const size_t base = (size_t)b * SLEN * DIMN + hh * HDN;
  const f16* Kp = Kh + base;
  const f16* Vp = VhT + (size_t)bh * 64 * SLEN;

  // Q fragments: col = q = l31, k = d = ks*16 + 8h + j
  f16x8 qb[4];
#pragma unroll
  for (int ks = 0; ks < 4; ++ks)
    qb[ks] = *(const f16x8*)(Qh + base + (size_t)(q0 + w * 32 + l31) * DIMN + ks * 16 + h * 8);

  // stage premultiplied mask bias (f32): BiasF[s] = mask[b][s] * MB
  {
    const float* mrow = mask + (size_t)b * SLEN + tid * 8;
    f4 a0 = *(const f4*)mrow, a1 = *(const f4*)(mrow + 4);
    f4 b0, b1;
#pragma unroll
    for (int i = 0; i < 4; ++i) { b0[i] = a0[i] * MB; b1[i] = a1[i] * MB; }
    *(f4*)&BiasF[tid * 8] = b0;
    *(f4*)&BiasF[tid * 8 + 4] = b1;
  }

  f32x16 O[2];
#pragma unroll
  for (int dg = 0; dg < 2; ++dg)
#pragma unroll
    for (int i = 0; i < 16; ++i) O[dg][i] = 0.f;
  float m_run = -1e30f, l_run = 0.f;

  const int srow = tid >> 3;
  const int csw = (tid & 7) ^ (srow & 7);

#define STAGE(buf, t)                                                                             \
  do {                                                                                            \
    _Pragma("unroll")                                                                             \
    for (int j = 0; j < 2; ++j) {                                                                 \
      int row = srow + j * 32;                                                                    \
      __builtin_amdgcn_global_load_lds(                                                           \
          (const __attribute__((address_space(1))) void*)(Kp + (size_t)((t) * 64 + row) * DIMN + csw * 8), \
          (__attribute__((address_space(3))) void*)&KVs[buf][0][j * 2048 + tid * 8], 16, 0, 0);   \
      __builtin_amdgcn_global_load_lds(                                                           \
          (const __attribute__((address_space(1))) void*)(Vp + (size_t)row * SLEN + (t) * 64 + csw * 8),   \
          (__attribute__((address_space(3))) void*)&KVs[buf][1][j * 2048 + tid * 8], 16, 0, 0);   \
    }                                                                                             \
  } while (0)

  STAGE(0, 0);
  asm volatile("s_waitcnt vmcnt(0) lgkmcnt(0)\n\ts_barrier" ::: "memory");

  for (int kt = 0; kt < NKT; ++kt) {
    const int cur = kt & 1;
    if (kt + 1 < NKT) STAGE(cur ^ 1, kt + 1);

    const f16* kb = KVs[cur][0];
    const f16* vb = KVs[cur][1];

    // bias for this lane's keys: key = 32rg + 8g + 4h + i  (f32, no cvt)
    f4 bk[2][4];
#pragma unroll
    for (int rg = 0; rg < 2; ++rg)
#pragma unroll
      for (int g = 0; g < 4; ++g)
        bk[rg][g] = *(const f4*)&BiasF[kt * 64 + rg * 32 + g * 8 + h * 4];

    // S^T[key][q] = K x Q^T : 2 key-groups x 4 k-steps of 32x32x16
    f32x16 sa[2];
#pragma unroll
    for (int kg = 0; kg < 2; ++kg)
#pragma unroll
      for (int i = 0; i < 16; ++i) sa[kg][i] = 0.f;
    __builtin_amdgcn_s_setprio(1);
#pragma unroll
    for (int ks = 0; ks < 4; ++ks) {
#pragma unroll
      for (int kg = 0; kg < 2; ++kg) {
        f16x8 ka = *(const f16x8*)&kb[(kg * 32 + l31) * 64 + (((2 * ks + h) ^ (l31 & 7)) * 8)];
        sa[kg] = __builtin_amdgcn_mfma_f32_32x32x16_f16(ka, qb[ks], sa[kg], 0, 0, 0);
      }
    }
    __builtin_amdgcn_s_setprio(0);

    // scale + premultiplied mask bias (exp2 domain)
#pragma unroll
    for (int rg = 0; rg < 2; ++rg)
#pragma unroll
      for (int g = 0; g < 4; ++g)
#pragma unroll
        for (int i = 0; i < 4; ++i)
          sa[rg][g * 4 + i] = __builtin_fmaf(sa[rg][g * 4 + i], K2, -bk[rg][g][i]);

    // per-q max over 64 keys: pairwise + nested triples (fuses to v_max3) + 1 shfl
    float tr[16];
#pragma unroll
    for (int i = 0; i < 16; ++i) tr[i] = fmaxf(sa[0][i], sa[1][i]);
    float u0 = fmaxf(fmaxf(tr[0], tr[1]), tr[2]);
    float u1 = fmaxf(fmaxf(tr[3], tr[4]), tr[5]);
    float u2 = fmaxf(fmaxf(tr[6], tr[7]), tr[8]);
    float u3 = fmaxf(fmaxf(tr[9], tr[10]), tr[11]);
    float u4 = fmaxf(fmaxf(tr[12], tr[13]), tr[14]);
    float t = fmaxf(fmaxf(fmaxf(u0, u1), u2), fmaxf(fmaxf(u3, u4), tr[15]));
    t = fmaxf(t, __shfl_xor(t, 32));
    if (__any(t > m_run + THR)) {
      float newm = fmaxf(m_run, t);
      float c = __builtin_amdgcn_exp2f(m_run - newm);
      m_run = newm;
      l_run *= c;
#pragma unroll
      for (int dg = 0; dg < 2; ++dg)
#pragma unroll
        for (int i = 0; i < 16; ++i) O[dg][i] *= c;
    }
    // P = exp2(sa - m); row-sum via tree
#pragma unroll
    for (int rg = 0; rg < 2; ++rg)
#pragma unroll
      for (int i = 0; i < 16; ++i)
        sa[rg][i] = __builtin_amdgcn_exp2f(sa[rg][i] - m_run);
    float sr[16];
#pragma unroll
    for (int i = 0; i < 16; ++i) sr[i] = sa[0][i] + sa[1][i];
#pragma unroll
    for (int i = 0; i < 8; ++i) sr[i] += sr[i + 8];
#pragma unroll
    for (int i = 0; i < 4; ++i) sr[i] += sr[i + 4];
    float ps = (sr[0] + sr[1]) + (sr[2] + sr[3]);
    ps += __shfl_xor(ps, 32);
    l_run += ps;

    // pack P: wv[rg][2g+c] covers keys 32rg + 8g + 4h + {2c,2c+1}
    unsigned int wv[2][8];
#pragma unroll
    for (int rg = 0; rg < 2; ++rg)
#pragma unroll
      for (int g = 0; g < 4; ++g) {
        wv[rg][2 * g]     = pk2u(sa[rg][4 * g],     sa[rg][4 * g + 1]);
        wv[rg][2 * g + 1] = pk2u(sa[rg][4 * g + 2], sa[rg][4 * g + 3]);
      }

    // O^T += V^T x P^T
#pragma unroll
    for (int ks = 0; ks < 4; ++ks) {
      const int rg = ks >> 1, K = ks & 1;
      unsigned int o0 = h ? wv[rg][4 * K + 2] : wv[rg][4 * K + 0];
      unsigned int o1 = h ? wv[rg][4 * K + 3] : wv[rg][4 * K + 1];
      unsigned int s0 = h ? wv[rg][4 * K + 0] : wv[rg][4 * K + 2];
      unsigned int s1 = h ? wv[rg][4 * K + 1] : wv[rg][4 * K + 3];
      unsigned int x0 = __shfl_xor(s0, 32);
      unsigned int x1 = __shfl_xor(s1, 32);
      u32x4 fv;
      fv[0] = h ? x0 : o0;
      fv[1] = h ? x1 : o1;
      fv[2] = h ? o0 : x0;
      fv[3] = h ? o1 : x1;
      f16x8 pfrag = __builtin_bit_cast(f16x8, fv);
      __builtin_amdgcn_s_setprio(1);
#pragma unroll
      for (int dg = 0; dg < 2; ++dg) {
        f16x8 va = *(const f16x8*)&vb[(dg * 32 + l31) * 64 + (((2 * ks + h) ^ (l31 & 7)) * 8)];
        O[dg] = __builtin_amdgcn_mfma_f32_32x32x16_f16(va, pfrag, O[dg], 0, 0, 0);
      }
      __builtin_amdgcn_s_setprio(0);
    }

    asm volatile("s_waitcnt vmcnt(0)\n\ts_barrier" ::: "memory");
  }

  // epilogue: O^T[d][q] -> att[q][d]
  float inv = 1.0f / l_run;
  const int q = q0 + w * 32 + l31;
#pragma unroll
  for (int dg = 0; dg < 2; ++dg)
#pragma unroll
    for (int g = 0; g < 4; ++g) {
      *(f16x4*)(att + base + (size_t)q * DIMN + dg * 32 + g * 8 + h * 4) =
          pk4(O[dg][4 * g] * inv, O[dg][4 * g + 1] * inv,
              O[dg][4 * g + 2] * inv, O[dg][4 * g + 3] * inv);
    }
#undef STAGE
}

extern "C" void kernel_launch(void* const* d_in, const int* in_sizes, int n_in,
                              void* d_out, int out_size, void* d_ws, size_t ws_size,
                              hipStream_t stream) {
  const float* q  = (const float*)d_in[0];
  const float* k  = (const float*)d_in[1];
  const float* v  = (const float*)d_in[2];
  const float* mk = (const float*)d_in[3];
  const float* Wq = (const float*)d_in[4];
  const float* Wk = (const float*)d_in[5];
  const float* Wv = (const float*)d_in[6];
  const float* Wo = (const float*)d_in[7];
  char* ws = (char*)d_ws;
  // ws layout: WT(4x2MB=8MB) | Qh 16MB | Kh 16MB | VhT 16MB | att 16MB => 72MB
  f16* WT  = (f16*)ws;
  f16* Qh  = (f16*)(ws + ((size_t)8 << 20));
  f16* Kh  = (f16*)(ws + ((size_t)24 << 20));
  f16* VhT = (f16*)(ws + ((size_t)40 << 20));
  f16* att = (f16*)(ws + ((size_t)56 << 20));
  float* out = (float*)d_out;

  k_wt<<<dim3(16, 16, 4), 256, 0, stream>>>(Wq, Wk, Wv, Wo, WT);
  k_qkv<<<dim3(64, 24), 256, 0, stream>>>(q, k, v, WT, Qh, Kh, VhT);
  k_attn<<<1024, 256, 0, stream>>>(Qh, Kh, VhT, mk, att);
  k_gemm_out<<<dim3(64, 8), 256, 0, stream>>>(att, WT + (size_t)3 * DIMN * DIMN, out);
}

// Round 17
// 218.287 us; speedup vs baseline: 1.1081x; 1.1081x over previous
//
#include <hip/hip_runtime.h>
#include <stdint.h>

#define DIMN 1024
#define HDN 64
#define SLEN 2048
#define NKT (SLEN / 64)

typedef _Float16 f16;
typedef __attribute__((ext_vector_type(8))) _Float16 f16x8;
typedef __attribute__((ext_vector_type(4))) _Float16 f16x4;
typedef __attribute__((ext_vector_type(2))) _Float16 f16x2;
typedef __attribute__((ext_vector_type(2))) __fp16 h16x2;   // cvt_pkrtz's native type
typedef __attribute__((ext_vector_type(4))) float f32x4;
typedef __attribute__((ext_vector_type(16))) float f32x16;
typedef __attribute__((ext_vector_type(4))) float f4;
typedef __attribute__((ext_vector_type(4))) unsigned int u32x4;

#define PA 48   // GEMM A LDS row stride (elems), 96B

__device__ __forceinline__ f16x2 pk2(float a, float b) {
  h16x2 t = __builtin_amdgcn_cvt_pkrtz(a, b);
  return __builtin_bit_cast(f16x2, t);
}
__device__ __forceinline__ unsigned int pk2u(float a, float b) {
  h16x2 t = __builtin_amdgcn_cvt_pkrtz(a, b);
  return __builtin_bit_cast(unsigned int, t);
}
__device__ __forceinline__ f16x4 pk4(float a, float b, float c, float d) {
  f16x2 x = pk2(a, b), y = pk2(c, d);
  f16x4 r; r[0] = x[0]; r[1] = x[1]; r[2] = y[0]; r[3] = y[1]; return r;
}
__device__ __forceinline__ f16x8 pk8(f4 x, f4 y) {
  f16x2 a = pk2(x[0], x[1]), b = pk2(x[2], x[3]);
  f16x2 c = pk2(y[0], y[1]), d = pk2(y[2], y[3]);
  f16x8 r; r[0] = a[0]; r[1] = a[1]; r[2] = b[0]; r[3] = b[1];
  r[4] = c[0]; r[5] = c[1]; r[6] = d[0]; r[7] = d[1]; return r;
}

// ---------- transpose + convert weights: WT[n][k] = (f16)W[k][n] ----------
__global__ __launch_bounds__(256) void k_wt(const float* __restrict__ W0, const float* __restrict__ W1,
                                            const float* __restrict__ W2, const float* __restrict__ W3,
                                            f16* __restrict__ WT) {
  __shared__ f16 tile[64][65];
  const float* W = (blockIdx.z == 0) ? W0 : (blockIdx.z == 1) ? W1 : (blockIdx.z == 2) ? W2 : W3;
  f16* T = WT + (size_t)blockIdx.z * DIMN * DIMN;
  int n0 = blockIdx.x * 64, k0 = blockIdx.y * 64;
  int tx = threadIdx.x & 63, ty = threadIdx.x >> 6;
  for (int i = ty; i < 64; i += 4)
    tile[i][tx] = (f16)(W[(size_t)(k0 + i) * DIMN + n0 + tx]);
  __syncthreads();
  for (int i = ty; i < 64; i += 4)
    T[(size_t)(n0 + i) * DIMN + k0 + tx] = tile[tx][i];
}

// ---------- fused QKV projection: one dispatch, 3 GEMMs (R12-exact, best wall) ----------
// Natural dispatch order. widx = by>>3 selects {q,k,v}. Do NOT add: XCD swizzle
// (R14: FETCH 4x, +59us), T14 pipeline (R15: +9us), split dispatches (R13: +18us).
__global__ __launch_bounds__(256) void k_qkv(const float* __restrict__ qin, const float* __restrict__ kin,
                                             const float* __restrict__ vin, const f16* __restrict__ WT,
                                             f16* __restrict__ Qh, f16* __restrict__ Kh,
                                             f16* __restrict__ VhT) {
  __shared__ alignas(16) f16 As[128 * PA];
  __shared__ alignas(16) f16 Bs[128 * 32];
  const int tid = threadIdx.x;
  const int lane = tid & 63, wid = tid >> 6;
  const int wr = wid >> 1, wc = wid & 1;
  const int l15 = lane & 15, lhi = lane >> 4;
  const int widx = blockIdx.y >> 3;
  const float* A = (widx == 0) ? qin : (widx == 1) ? kin : vin;
  const f16* BT = WT + (size_t)widx * DIMN * DIMN;
  const int m0 = blockIdx.x * 128, n0 = (blockIdx.y & 7) * 128;
  const int r0 = tid >> 2, c0 = tid & 3;

  f32x4 acc[4][4];
#pragma unroll
  for (int i = 0; i < 4; ++i)
#pragma unroll
    for (int j = 0; j < 4; ++j) { f32x4 z = {0.f, 0.f, 0.f, 0.f}; acc[i][j] = z; }

  for (int kt = 0; kt < DIMN; kt += 32) {
    __syncthreads();
#pragma unroll
    for (int hh = 0; hh < 2; ++hh) {
      int row = hh * 64 + r0;
      __builtin_amdgcn_global_load_lds(
          (const __attribute__((address_space(1))) void*)(BT + (size_t)(n0 + row) * DIMN + kt + c0 * 8),
          (__attribute__((address_space(3))) void*)&Bs[hh * 2048 + tid * 8], 16, 0, 0);
    }
#pragma unroll
    for (int hh = 0; hh < 2; ++hh) {
      int row = r0 + hh * 64;
      const f4* src = (const f4*)(A + (size_t)(m0 + row) * DIMN + kt + c0 * 8);
      f4 a0 = src[0], a1 = src[1];
      *(f16x8*)&As[row * PA + c0 * 8] = pk8(a0, a1);
    }
    __syncthreads();
    f16x8 af[4], bb[4];
#pragma unroll
    for (int mf = 0; mf < 4; ++mf) {
      int row = wr * 64 + mf * 16 + l15;
      af[mf] = *(const f16x8*)&As[row * PA + lhi * 8];
    }
#pragma unroll
    for (int nf = 0; nf < 4; ++nf) {
      int row = wc * 64 + nf * 16 + l15;
      bb[nf] = *(const f16x8*)&Bs[row * 32 + lhi * 8];
    }
#pragma unroll
    for (int mf = 0; mf < 4; ++mf)
#pragma unroll
      for (int nf = 0; nf < 4; ++nf)
        acc[mf][nf] = __builtin_amdgcn_mfma_f32_16x16x32_f16(af[mf], bb[nf], acc[mf][nf], 0, 0, 0);
  }

  if (widx == 2) {
    // V: store C^T per head -> VhT[bh][d][s], s-packed f16x4
#pragma unroll
    for (int mf = 0; mf < 4; ++mf) {
      int rowbase = m0 + wr * 64 + mf * 16 + lhi * 4;
      int bq = rowbase >> 11, sl = rowbase & 2047;
#pragma unroll
      for (int nf = 0; nf < 4; ++nf) {
        int col = n0 + wc * 64 + nf * 16 + l15;
        int bh = bq * 16 + (col >> 6), d = col & 63;
        *(f16x4*)&VhT[((size_t)bh * 64 + d) * SLEN + sl] =
            pk4(acc[mf][nf][0], acc[mf][nf][1], acc[mf][nf][2], acc[mf][nf][3]);
      }
    }
  } else {
    f16* Cp = widx ? Kh : Qh;
#pragma unroll
    for (int mf = 0; mf < 4; ++mf)
#pragma unroll
      for (int r = 0; r < 4; ++r) {
        int row = m0 + wr * 64 + mf * 16 + lhi * 4 + r;
#pragma unroll
        for (int nf = 0; nf < 4; ++nf) {
          int col = n0 + wc * 64 + nf * 16 + l15;
          Cp[(size_t)row * DIMN + col] = (f16)acc[mf][nf][r];
        }
      }
  }
}

// ---------- out-projection GEMM: out[M,1024] f32 = att @ WoT ----------
__global__ __launch_bounds__(256) void k_gemm_out(const f16* __restrict__ A,
                                                  const f16* __restrict__ BT,
                                                  float* __restrict__ Cp) {
  __shared__ alignas(16) f16 As[128 * PA];
  __shared__ alignas(16) f16 Bs[128 * 32];
  const int tid = threadIdx.x;
  const int lane = tid & 63, wid = tid >> 6;
  const int wr = wid >> 1, wc = wid & 1;
  const int l15 = lane & 15, lhi = lane >> 4;
  const int m0 = blockIdx.x * 128, n0 = blockIdx.y * 128;
  const int r0 = tid >> 2, c0 = tid & 3;

  f32x4 acc[4][4];
#pragma unroll
  for (int i = 0; i < 4; ++i)
#pragma unroll
    for (int j = 0; j < 4; ++j) { f32x4 z = {0.f, 0.f, 0.f, 0.f}; acc[i][j] = z; }

  for (int kt = 0; kt < DIMN; kt += 32) {
    __syncthreads();
#pragma unroll
    for (int hh = 0; hh < 2; ++hh) {
      int row = hh * 64 + r0;
      __builtin_amdgcn_global_load_lds(
          (const __attribute__((address_space(1))) void*)(BT + (size_t)(n0 + row) * DIMN + kt + c0 * 8),
          (__attribute__((address_space(3))) void*)&Bs[hh * 2048 + tid * 8], 16, 0, 0);
    }
#pragma unroll
    for (int hh = 0; hh < 2; ++hh) {
      int row = r0 + hh * 64;
      f16x8 vv = *(const f16x8*)(A + (size_t)(m0 + row) * DIMN + kt + c0 * 8);
      *(f16x8*)&As[row * PA + c0 * 8] = vv;
    }
    __syncthreads();
    f16x8 af[4], bb[4];
#pragma unroll
    for (int mf = 0; mf < 4; ++mf) {
      int row = wr * 64 + mf * 16 + l15;
      af[mf] = *(const f16x8*)&As[row * PA + lhi * 8];
    }
#pragma unroll
    for (int nf = 0; nf < 4; ++nf) {
      int row = wc * 64 + nf * 16 + l15;
      bb[nf] = *(const f16x8*)&Bs[row * 32 + lhi * 8];
    }
#pragma unroll
    for (int mf = 0; mf < 4; ++mf)
#pragma unroll
      for (int nf = 0; nf < 4; ++nf)
        acc[mf][nf] = __builtin_amdgcn_mfma_f32_16x16x32_f16(af[mf], bb[nf], acc[mf][nf], 0, 0, 0);
  }
#pragma unroll
  for (int mf = 0; mf < 4; ++mf)
#pragma unroll
    for (int r = 0; r < 4; ++r) {
      int row = m0 + wr * 64 + mf * 16 + lhi * 4 + r;
#pragma unroll
      for (int nf = 0; nf < 4; ++nf) {
        int col = n0 + wc * 64 + nf * 16 + l15;
        Cp[(size_t)row * DIMN + col] = acc[mf][nf][r];
      }
    }
}

// ---------- flash attention: R12-exact (4 blocks/CU, f16 bias, tree max) ----------
// Do NOT add: f32 bias or max3 rewrite (R16: +14us — extra LDS bytes in the
// critical phase cost more than the VALU saved).
__global__ __launch_bounds__(256, 4) void k_attn(const f16* __restrict__ Qh, const f16* __restrict__ Kh,
                                                 const f16* __restrict__ VhT, const float* __restrict__ mask,
                                                 f16* __restrict__ att) {
  __shared__ alignas(16) f16 KVs[2][2][64 * 64];  // [buf][K=0/V=1][row][64]
  __shared__ alignas(16) f16 BiasH[SLEN];         // 30000 * mask, f16

  const int tid = threadIdx.x;
  const int lane = tid & 63, w = tid >> 6;
  const int l31 = lane & 31, h = lane >> 5;

  const float K2 = 0.18033688f;          // 0.125 * log2(e)
  const float THR = 11.541560f;          // 8 * log2(e)

  const int id = blockIdx.x;
  const int xcd = id & 7, slot = id >> 3;
  const int qt = slot & 15;
  const int bh = xcd * 8 + (slot >> 4);
  const int b = bh >> 4, hh = bh & 15;
  const int q0 = qt * 128;
  const size_t base = (size_t)b * SLEN * DIMN + hh * HDN;
  const f16* Kp = Kh + base;
  const f16* Vp = VhT + (size_t)bh * 64 * SLEN;

  // Q fragments: col = q = l31, k = d = ks*16 + 8h + j
  f16x8 qb[4];
#pragma unroll
  for (int ks = 0; ks < 4; ++ks)
    qb[ks] = *(const f16x8*)(Qh + base + (size_t)(q0 + w * 32 + l31) * DIMN + ks * 16 + h * 8);

  // stage premultiplied mask bias: BiasH[s] = (f16)(mask[b][s] * 30000)
  {
    const float* mrow = mask + (size_t)b * SLEN + tid * 8;
    f4 a0 = *(const f4*)mrow, a1 = *(const f4*)(mrow + 4);
    f4 b0, b1;
#pragma unroll
    for (int i = 0; i < 4; ++i) { b0[i] = a0[i] * 30000.0f; b1[i] = a1[i] * 30000.0f; }
    *(f16x8*)&BiasH[tid * 8] = pk8(b0, b1);
  }

  f32x16 O[2];
#pragma unroll
  for (int dg = 0; dg < 2; ++dg)
#pragma unroll
    for (int i = 0; i < 16; ++i) O[dg][i] = 0.f;
  float m_run = -1e30f, l_run = 0.f;

  const int srow = tid >> 3;
  const int csw = (tid & 7) ^ (srow & 7);

#define STAGE(buf, t)                                                                             \
  do {                                                                                            \
    _Pragma("unroll")                                                                             \
    for (int j = 0; j < 2; ++j) {                                                                 \
      int row = srow + j * 32;                                                                    \
      __builtin_amdgcn_global_load_lds(                                                           \
          (const __attribute__((address_space(1))) void*)(Kp + (size_t)((t) * 64 + row) * DIMN + csw * 8), \
          (__attribute__((address_space(3))) void*)&KVs[buf][0][j * 2048 + tid * 8], 16, 0, 0);   \
      __builtin_amdgcn_global_load_lds(                                                           \
          (const __attribute__((address_space(1))) void*)(Vp + (size_t)row * SLEN + (t) * 64 + csw * 8),   \
          (__attribute__((address_space(3))) void*)&KVs[buf][1][j * 2048 + tid * 8], 16, 0, 0);   \
    }                                                                                             \
  } while (0)

  STAGE(0, 0);
  asm volatile("s_waitcnt vmcnt(0) lgkmcnt(0)\n\ts_barrier" ::: "memory");

  for (int kt = 0; kt < NKT; ++kt) {
    const int cur = kt & 1;
    if (kt + 1 < NKT) STAGE(cur ^ 1, kt + 1);

    const f16* kb = KVs[cur][0];
    const f16* vb = KVs[cur][1];

    // bias for this lane's keys: key = 32rg + 8g + 4h + i
    f4 bk[2][4];
#pragma unroll
    for (int rg = 0; rg < 2; ++rg)
#pragma unroll
      for (int g = 0; g < 4; ++g) {
        f16x4 b4 = *(const f16x4*)&BiasH[kt * 64 + rg * 32 + g * 8 + h * 4];
#pragma unroll
        for (int i = 0; i < 4; ++i) bk[rg][g][i] = (float)b4[i];
      }

    // S^T[key][q] = K x Q^T : 2 key-groups x 4 k-steps of 32x32x16
    f32x16 sa[2];
#pragma unroll
    for (int kg = 0; kg < 2; ++kg)
#pragma unroll
      for (int i = 0; i < 16; ++i) sa[kg][i] = 0.f;
    __builtin_amdgcn_s_setprio(1);
#pragma unroll
    for (int ks = 0; ks < 4; ++ks) {
#pragma unroll
      for (int kg = 0; kg < 2; ++kg) {
        f16x8 ka = *(const f16x8*)&kb[(kg * 32 + l31) * 64 + (((2 * ks + h) ^ (l31 & 7)) * 8)];
        sa[kg] = __builtin_amdgcn_mfma_f32_32x32x16_f16(ka, qb[ks], sa[kg], 0, 0, 0);
      }
    }
    __builtin_amdgcn_s_setprio(0);

    // scale + premultiplied mask bias (exp2 domain)
#pragma unroll
    for (int rg = 0; rg < 2; ++rg)
#pragma unroll
      for (int g = 0; g < 4; ++g)
#pragma unroll
        for (int i = 0; i < 4; ++i)
          sa[rg][g * 4 + i] = __builtin_fmaf(sa[rg][g * 4 + i], K2, -bk[rg][g][i]);

    // per-q max over 64 keys: tree + 1 shfl_xor(32)
    float tr[16];
#pragma unroll
    for (int i = 0; i < 16; ++i) tr[i] = fmaxf(sa[0][i], sa[1][i]);
#pragma unroll
    for (int i = 0; i < 8; ++i) tr[i] = fmaxf(tr[i], tr[i + 8]);
#pragma unroll
    for (int i = 0; i < 4; ++i) tr[i] = fmaxf(tr[i], tr[i + 4]);
    float t = fmaxf(fmaxf(tr[0], tr[1]), fmaxf(tr[2], tr[3]));
    t = fmaxf(t, __shfl_xor(t, 32));
    if (__any(t > m_run + THR)) {
      float newm = fmaxf(m_run, t);
      float c = __builtin_amdgcn_exp2f(m_run - newm);
      m_run = newm;
      l_run *= c;
#pragma unroll
      for (int dg = 0; dg < 2; ++dg)
#pragma unroll
        for (int i = 0; i < 16; ++i) O[dg][i] *= c;
    }
    // P = exp2(sa - m); row-sum via tree
#pragma unroll
    for (int rg = 0; rg < 2; ++rg)
#pragma unroll
      for (int i = 0; i < 16; ++i)
        sa[rg][i] = __builtin_amdgcn_exp2f(sa[rg][i] - m_run);
    float sr[16];
#pragma unroll
    for (int i = 0; i < 16; ++i) sr[i] = sa[0][i] + sa[1][i];
#pragma unroll
    for (int i = 0; i < 8; ++i) sr[i] += sr[i + 8];
#pragma unroll
    for (int i = 0; i < 4; ++i) sr[i] += sr[i + 4];
    float ps = (sr[0] + sr[1]) + (sr[2] + sr[3]);
    ps += __shfl_xor(ps, 32);
    l_run += ps;

    // pack P: wv[rg][2g+c] covers keys 32rg + 8g + 4h + {2c,2c+1}
    unsigned int wv[2][8];
#pragma unroll
    for (int rg = 0; rg < 2; ++rg)
#pragma unroll
      for (int g = 0; g < 4; ++g) {
        wv[rg][2 * g]     = pk2u(sa[rg][4 * g],     sa[rg][4 * g + 1]);
        wv[rg][2 * g + 1] = pk2u(sa[rg][4 * g + 2], sa[rg][4 * g + 3]);
      }

    // O^T += V^T x P^T
#pragma unroll
    for (int ks = 0; ks < 4; ++ks) {
      const int rg = ks >> 1, K = ks & 1;
      unsigned int o0 = h ? wv[rg][4 * K + 2] : wv[rg][4 * K + 0];
      unsigned int o1 = h ? wv[rg][4 * K + 3] : wv[rg][4 * K + 1];
      unsigned int s0 = h ? wv[rg][4 * K + 0] : wv[rg][4 * K + 2];
      unsigned int s1 = h ? wv[rg][4 * K + 1] : wv[rg][4 * K + 3];
      unsigned int x0 = __shfl_xor(s0, 32);
      unsigned int x1 = __shfl_xor(s1, 32);
      u32x4 fv;
      fv[0] = h ? x0 : o0;
      fv[1] = h ? x1 : o1;
      fv[2] = h ? o0 : x0;
      fv[3] = h ? o1 : x1;
      f16x8 pfrag = __builtin_bit_cast(f16x8, fv);
      __builtin_amdgcn_s_setprio(1);
#pragma unroll
      for (int dg = 0; dg < 2; ++dg) {
        f16x8 va = *(const f16x8*)&vb[(dg * 32 + l31) * 64 + (((2 * ks + h) ^ (l31 & 7)) * 8)];
        O[dg] = __builtin_amdgcn_mfma_f32_32x32x16_f16(va, pfrag, O[dg], 0, 0, 0);
      }
      __builtin_amdgcn_s_setprio(0);
    }

    asm volatile("s_waitcnt vmcnt(0)\n\ts_barrier" ::: "memory");
  }

  // epilogue: O^T[d][q] -> att[q][d]
  float inv = 1.0f / l_run;
  const int q = q0 + w * 32 + l31;
#pragma unroll
  for (int dg = 0; dg < 2; ++dg)
#pragma unroll
    for (int g = 0; g < 4; ++g) {
      *(f16x4*)(att + base + (size_t)q * DIMN + dg * 32 + g * 8 + h * 4) =
          pk4(O[dg][4 * g] * inv, O[dg][4 * g + 1] * inv,
              O[dg][4 * g + 2] * inv, O[dg][4 * g + 3] * inv);
    }
#undef STAGE
}

extern "C" void kernel_launch(void* const* d_in, const int* in_sizes, int n_in,
                              void* d_out, int out_size, void* d_ws, size_t ws_size,
                              hipStream_t stream) {
  const float* q  = (const float*)d_in[0];
  const float* k  = (const float*)d_in[1];
  const float* v  = (const float*)d_in[2];
  const float* mk = (const float*)d_in[3];
  const float* Wq = (const float*)d_in[4];
  const float* Wk = (const float*)d_in[5];
  const float* Wv = (const float*)d_in[6];
  const float* Wo = (const float*)d_in[7];
  char* ws = (char*)d_ws;
  // ws layout: WT(4x2MB=8MB) | Qh 16MB | Kh 16MB | VhT 16MB | att 16MB => 72MB
  f16* WT  = (f16*)ws;
  f16* Qh  = (f16*)(ws + ((size_t)8 << 20));
  f16* Kh  = (f16*)(ws + ((size_t)24 << 20));
  f16* VhT = (f16*)(ws + ((size_t)40 << 20));
  f16* att = (f16*)(ws + ((size_t)56 << 20));
  float* out = (float*)d_out;

  k_wt<<<dim3(16, 16, 4), 256, 0, stream>>>(Wq, Wk, Wv, Wo, WT);
  k_qkv<<<dim3(64, 24), 256, 0, stream>>>(q, k, v, WT, Qh, Kh, VhT);
  k_attn<<<1024, 256, 0, stream>>>(Qh, Kh, VhT, mk, att);
  k_gemm_out<<<dim3(64, 8), 256, 0, stream>>>(att, WT + (size_t)3 * DIMN * DIMN, out);
}